// Round 6
// baseline (186.259 us; speedup 1.0000x reference)
//
#include <hip/hip_runtime.h>
#include <hip/hip_fp16.h>
#include <math.h>

// FBP adjoint as dense f16 MFMA GEMM.
//   out[b,i0,i1,i2] = (1/A) * sum_{j,k} W[(i0,i2),(j,k)] * x[b,j,i1,k]
// C[M=1089, N=4224(i1*128+b)] = W[MxK] . Xt[NxK]^T, K=3993 padded to 4032.
// R15 = R14 with the cvt_pkrtz return-type compile fix (bit_cast directly,
// don't name the builtin's __fp16x2 type). R14 rationale: gemm FROZEN at
// R13 form (70.9us, FETCH 77MB, MfmaUtil 21.6% = latency-structural;
// pipelining regressed twice). Lever is prep (<71us measured bound vs 20us
// roofline): old xt loop had stride-2-dword gather lanes + per-element
// magic-div. New: LDS-staged transpose, block=(b, 8-j group): read 8x1089
// contiguous floats coalesced -> f16 LDS -> write 33 i1-rows x 132
// contiguous dwords. Elementwise RTZ = bit-identical Xt.

#define PDIM 33
#define PP   1089
#define A_   121
#define K_   3993
#define KP   4032
#define MP   1152            // padded M (18*64)
#define MT2  18              // M tiles (64)
#define NT2  66              // N tiles (64) = 33 i1 * 2 b-halves
#define NWG  1188            // MT2*NT2
#define OUTB 35937           // 33*33*33
#define XTB  2048            // 128 b * 16 j-groups

typedef _Float16 f16x8 __attribute__((ext_vector_type(8)));
typedef float    f32x4 __attribute__((ext_vector_type(4)));
typedef _Float16 h2v   __attribute__((ext_vector_type(2)));

typedef __attribute__((address_space(1))) const unsigned int* gp_t;
typedef __attribute__((address_space(3))) unsigned int*       lp_t;

static __device__ __forceinline__ unsigned short cvt1_rtz(float v)
{
    return (unsigned short)__builtin_bit_cast(unsigned int,
               __builtin_amdgcn_cvt_pkrtz(v, v));
}

// ---------------- fused prep: Xt transpose-pack + W fill ----------------

__global__ __launch_bounds__(256)
void prep_kernel(const float* __restrict__ x, const float* __restrict__ angles,
                 __half* __restrict__ Xt, __half* __restrict__ W)
{
    __shared__ unsigned short lh[8712];      // 8 j-rows of [33 i1][33 k] f16
    const int blk = blockIdx.x;
    const int t   = threadIdx.x;

    if (blk < XTB) {
        // ---- Xt pack, block = (b, j-group g). x[b,j,i1,k] -> Xt[(i1,b)][j,k]
        const int b = blk >> 4;
        const int g = blk & 15;
        const float* src = x + (size_t)b * (A_ * PP);
        if (g < 15) {
            // j in [8g, 8g+8): read 8712 contiguous floats, coalesced.
            src += (size_t)g * 8712;
            for (int e = t; e < 8712; e += 256)
                lh[e] = cvt1_rtz(src[e]);
            __syncthreads();
            // write: 33 i1-rows x 132 dwords contiguous at kk = g*264
            for (int e = t; e < 4356; e += 256) {
                int i1 = e / 132;
                int d  = e - i1 * 132;
                int le0 = 2 * d, le1 = le0 + 1;
                int j0 = le0 / 33, k0 = le0 - j0 * 33;
                int j1 = le1 / 33, k1 = le1 - j1 * 33;
                unsigned int lo = lh[j0 * PP + i1 * PDIM + k0];
                unsigned int hi = lh[j1 * PP + i1 * PDIM + k1];
                unsigned int* drow = (unsigned int*)
                    (Xt + (size_t)(i1 * 128 + b) * KP + g * 264);
                drow[d] = lo | (hi << 16);
            }
        } else {
            // remainder j=120 + zero-pad kk in [3960, 4032)
            src += (size_t)120 * PP;
            for (int e = t; e < PP; e += 256)
                lh[e] = cvt1_rtz(src[e]);
            __syncthreads();
            for (int e = t; e < 33 * 36; e += 256) {
                int i1 = e / 36;
                int d  = e - i1 * 36;
                int k0 = 2 * d, k1 = k0 + 1;
                unsigned int lo = (k0 < PDIM) ? (unsigned int)lh[i1 * PDIM + k0] : 0u;
                unsigned int hi = (k1 < PDIM) ? (unsigned int)lh[i1 * PDIM + k1] : 0u;
                unsigned int* drow = (unsigned int*)
                    (Xt + (size_t)(i1 * 128 + b) * KP + 3960);
                drow[d] = lo | (hi << 16);
            }
        }
    } else {
        // ---- W row n: zero-fill (int4) then scatter the 2 bilinear taps/angle.
        const int n = blk - XTB;             // 0..1151
        __half* row = W + (size_t)n * KP;    // 8064 B, 16B-aligned
        int4 zz = make_int4(0, 0, 0, 0);
        for (int e = t; e < KP / 8; e += 256)
            ((int4*)row)[e] = zz;
        __syncthreads();
        if (n >= PP || t >= A_) return;
        const int j  = t;
        const int i0 = n / PDIM;
        const int i2 = n - i0 * PDIM;
        float s, c;
        sincosf(angles[j], &s, &c);
        float ix = fmaf((float)(i2 - 16), c, fmaf((float)(i0 - 16), s, 16.0f));
        float fl = floorf(ix);
        int   k0 = (int)fl;
        float w1 = ix - fl;
        float w0 = 1.0f - w1;
        __half* seg = row + j * PDIM;
        if (k0 >= 0     && k0 < PDIM)     seg[k0]     = __float2half_rn(w0);
        if (k0 + 1 >= 0 && k0 + 1 < PDIM) seg[k0 + 1] = __float2half_rn(w1);
    }
}

// GEMM: C = W . Xt^T, 64x64 tile, BK=64, 4 waves (2x2), 32x32 per wave.
// R9 2-barrier loop (compiler-scheduled) + R13 XCD-chunked tile mapping.
// FROZEN: 70.9us, FETCH 77MB, MfmaUtil 21.6% (R13 measured).
__global__ __launch_bounds__(256)
void gemm_kernel(const __half* __restrict__ W, const __half* __restrict__ Xt,
                 float* __restrict__ out, float invA)
{
    __shared__ _Float16 As[64 * 64];     // 8 KB, chunk-swizzled
    __shared__ _Float16 Bs[64 * 64];     // 8 KB

    // ---- XCD-aware bijective remap (blk%8 = XCD; nwg=1188: q=148,r=4) ----
    const int b0  = blockIdx.x;
    const int xcd = b0 & 7;
    const int pos = b0 >> 3;
    const int d   = (xcd < 4) ? xcd * 149 + pos
                              : 596 + (xcd - 4) * 148 + pos;
    int tileM, tileN;
    if (d < 324) {                       // chunks 0,1: 9 panels each
        int c = d / 162, l = d - c * 162;
        tileM = l / 9;
        tileN = c * 9 + (l - tileM * 9);
    } else {                             // chunks 2..7: 8 panels each
        int dd = d - 324;
        int c = dd / 144, l = dd - c * 144;
        tileM = l >> 3;
        tileN = 18 + c * 8 + (l & 7);
    }

    const int t     = threadIdx.x;
    const int lane  = t & 63;
    const int wave  = t >> 6;
    const int warpM = wave >> 1;
    const int warpN = wave & 1;
    const int quad  = lane >> 4;
    const int l15   = lane & 15;

    f32x4 acc[2][2] = {};

    const __half* Ab = W  + (size_t)(tileM * 64) * KP;
    const __half* Bb = Xt + (size_t)(tileN * 64) * KP;

    // Staging chunk geometry: chunk cidx (0..511) = 16B = (row=cidx>>3,
    // seg=cidx&7). Global k-seg fetched = seg ^ (row&7); LDS dest linear.
    int srow[2], ssego[2];
#pragma unroll
    for (int i = 0; i < 2; ++i) {
        int cidx = t + i * 256;
        int row  = cidx >> 3;
        int seg  = cidx & 7;
        srow[i]  = row;
        ssego[i] = (seg ^ (row & 7)) * 8;   // halves offset within K-slice
    }

    // Frag-read addresses (halves): row r, k-seg ks -> r*64 + (ks^(r&7))*8
    int arow[2], brow[2];
#pragma unroll
    for (int s = 0; s < 2; ++s) {
        arow[s] = warpM * 32 + s * 16 + l15;
        brow[s] = warpN * 32 + s * 16 + l15;
    }

    for (int kb = 0; kb < KP; kb += 64) {
        __syncthreads();
#pragma unroll
        for (int i = 0; i < 2; ++i) {
            const __half* ga = Ab + (size_t)srow[i] * KP + kb + ssego[i];
            const __half* gb = Bb + (size_t)srow[i] * KP + kb + ssego[i];
            __builtin_amdgcn_global_load_lds((gp_t)(const void*)ga,
                (lp_t)(void*)&As[(t + i * 256) * 8], 16, 0, 0);
            __builtin_amdgcn_global_load_lds((gp_t)(const void*)gb,
                (lp_t)(void*)&Bs[(t + i * 256) * 8], 16, 0, 0);
        }
        __syncthreads();

        f16x8 af[2][2], bf[2][2];
#pragma unroll
        for (int h = 0; h < 2; ++h) {
#pragma unroll
            for (int s = 0; s < 2; ++s) {
                int ks = h * 4 + quad;
                af[h][s] = *(const f16x8*)&As[arow[s] * 64 + ((ks ^ (arow[s] & 7)) * 8)];
                bf[h][s] = *(const f16x8*)&Bs[brow[s] * 64 + ((ks ^ (brow[s] & 7)) * 8)];
            }
        }
#pragma unroll
        for (int h = 0; h < 2; ++h)
#pragma unroll
            for (int ms = 0; ms < 2; ++ms)
#pragma unroll
                for (int ns = 0; ns < 2; ++ns)
                    acc[ms][ns] = __builtin_amdgcn_mfma_f32_16x16x32_f16(
                        af[h][ms], bf[h][ns], acc[ms][ns], 0, 0, 0);
    }

    // Epilogue: C row m=(i0,i2), col nglob=(i1*128+b); out[b,i0,i1,i2].
#pragma unroll
    for (int ns = 0; ns < 2; ++ns) {
        int nglob = tileN * 64 + warpN * 32 + ns * 16 + l15;
        int i1 = nglob >> 7;
        int b  = nglob & 127;
        float* ob = out + (size_t)b * OUTB + (size_t)i1 * PDIM;
#pragma unroll
        for (int ms = 0; ms < 2; ++ms) {
#pragma unroll
            for (int r = 0; r < 4; ++r) {
                int m = tileM * 64 + warpM * 32 + ms * 16 + quad * 4 + r;
                if (m < PP) {
                    int i0 = m / PDIM;
                    int i2 = m - i0 * PDIM;
                    ob[(size_t)i0 * PP + i2] = acc[ms][ns][r] * invA;
                }
            }
        }
    }
}

// ---------------- fallback (R6, proven ~151 us) ----------------

#define ROWW 47
#define PADL 7
#define BLK  384
#define NV   3
#define GRID 1280

#if defined(__has_builtin)
#if __has_builtin(__builtin_amdgcn_fractf)
#define FRACTF(x) __builtin_amdgcn_fractf(x)
#endif
#endif
#ifndef FRACTF
#define FRACTF(x) ((x) - floorf(x))
#endif

__device__ __forceinline__ float fdot2u(unsigned int a, unsigned int b, float c)
{
    return __builtin_amdgcn_fdot2(__builtin_bit_cast(h2v, a),
                                  __builtin_bit_cast(h2v, b), c, false);
}

__global__ __launch_bounds__(BLK)
void fbp_adjoint_kernel(const float* __restrict__ x,
                        const float* __restrict__ angles,
                        float* __restrict__ out,
                        int nslice, float invA)
{
    __shared__ unsigned int dr[A_ * ROWW];
    __shared__ float2       cs_lds[A_];

    const int t = threadIdx.x;
    for (int j = t; j < A_; j += BLK) {
        float s, c;
        sincosf(angles[j], &s, &c);
        cs_lds[j] = make_float2(c, s);
    }

    float u0[NV], u2[NV];
#pragma unroll
    for (int nn = 0; nn < NV; ++nn) {
        int n  = t + nn * BLK;
        int nc = (n < PP) ? n : (PP - 1);
        int q0 = nc / PDIM;
        int q2 = nc - q0 * PDIM;
        u0[nn] = (float)(q0 - 16);
        u2[nn] = (float)(q2 - 16);
    }

    for (int slice = blockIdx.x; slice < nslice; slice += GRID) {
        if (slice != (int)blockIdx.x) __syncthreads();
        const int hb = slice / PDIM;
        const int i1 = slice - hb * PDIM;
        const int b0 = 2 * hb;
        const float* r0 = x + (size_t)b0 * (A_ * PP) + (size_t)i1 * PDIM;
        const float* r1 = r0 + (size_t)(A_ * PP);
        for (int e = t; e < A_ * ROWW; e += BLK) {
            int j = e / ROWW;
            int p = e - j * ROWW;
            int k = p - PADL;
            float f0 = 0.0f, f1 = 0.0f;
            if (k >= 0 && k < PDIM) {
                size_t o = (size_t)j * PP + k;
                f0 = r0[o];
                f1 = r1[o];
            }
            dr[e] = __builtin_bit_cast(unsigned int,
                        __halves2half2(__float2half_rn(f0), __float2half_rn(f1)));
        }
        __syncthreads();

        float a0[NV] = {0.0f, 0.0f, 0.0f};
        float a1[NV] = {0.0f, 0.0f, 0.0f};
#pragma unroll 2
        for (int j = 0; j < A_; ++j) {
            float2 cj = cs_lds[j];
            const unsigned int* base = &dr[j * ROWW];
#pragma unroll
            for (int nn = 0; nn < NV; ++nn) {
                float ixp = fmaf(u2[nn], cj.x, fmaf(u0[nn], cj.y, 23.0f));
                int   kp  = (int)ixp;
                float w1  = FRACTF(ixp);
                unsigned int wp = __builtin_bit_cast(unsigned int,
                                    __builtin_amdgcn_cvt_pkrtz(1.0f - w1, w1));
                unsigned int d0 = base[kp];
                unsigned int d1 = base[kp + 1];
                unsigned int p0 = __builtin_amdgcn_perm(d1, d0, 0x05040100u);
                unsigned int p1 = __builtin_amdgcn_perm(d1, d0, 0x07060302u);
                a0[nn] = fdot2u(p0, wp, a0[nn]);
                a1[nn] = fdot2u(p1, wp, a1[nn]);
            }
        }

        float* ob0 = out + (size_t)b0 * OUTB + (size_t)i1 * PDIM;
        float* ob1 = ob0 + (size_t)OUTB;
#pragma unroll
        for (int nn = 0; nn < NV; ++nn) {
            int n = t + nn * BLK;
            if (n < PP) {
                int q0 = n / PDIM;
                int q2 = n - q0 * PDIM;
                size_t o = (size_t)q0 * PP + q2;
                ob0[o] = a0[nn] * invA;
                ob1[o] = a1[nn] * invA;
            }
        }
    }
}

// ---------------- launch ----------------

extern "C" void kernel_launch(void* const* d_in, const int* in_sizes, int n_in,
                              void* d_out, int out_size, void* d_ws, size_t ws_size,
                              hipStream_t stream)
{
    const float* x      = (const float*)d_in[0];
    const float* angles = (const float*)d_in[1];
    float* out          = (float*)d_out;

    const int A = in_sizes[1];                    // 121
    const int B = in_sizes[0] / (A * PP);         // 128
    const float invA = 1.0f / (float)A;

    const size_t wBytes  = (size_t)MP * KP * sizeof(__half);         // 9.29 MB
    const size_t xtBytes = (size_t)(PDIM * B) * KP * sizeof(__half); // 34.1 MB

    if (ws_size >= wBytes + xtBytes && A == A_ && B == 128) {
        __half* W  = (__half*)d_ws;
        __half* Xt = (__half*)((char*)d_ws + wBytes);
        prep_kernel<<<XTB + MP, 256, 0, stream>>>(x, angles, Xt, W);
        gemm_kernel<<<NWG, 256, 0, stream>>>(W, Xt, out, invA);
    } else {
        const int nslice = (B / 2) * PDIM;
        dim3 grid(GRID < nslice ? GRID : nslice);
        fbp_adjoint_kernel<<<grid, BLK, 0, stream>>>(x, angles, out,
                                                     nslice, invA);
    }
}